// Round 2
// baseline (1140.859 us; speedup 1.0000x reference)
//
#include <hip/hip_runtime.h>
#include <math.h>

// Problem constants (fixed shapes from reference setup_inputs)
constexpr int BB  = 2;
constexpr int NN  = 16384;
constexpr int KK  = 32;     // neighbors
constexpr int CC  = 128;    // channels (C_in == C_out)
constexpr int GEO = 10;
#define LN_EPS 1e-5f

__global__ __launch_bounds__(CC) void bridge_kernel(
    const float* __restrict__ points,    // (B,N,3)
    const float* __restrict__ features,  // (B,N,C)
    const int*   __restrict__ gidx,      // (B,N,K)
    const float* __restrict__ w_pos,     // (GEO,C)
    const float* __restrict__ b_pos,     // (C)
    const float* __restrict__ w_gcm,     // (C,C)
    const float* __restrict__ b_gcm,     // (C)
    const float* __restrict__ w_out,     // (C,C)
    const float* __restrict__ b_out,     // (C)
    const float* __restrict__ ln_g,      // (C)
    const float* __restrict__ ln_b,      // (C)
    float* __restrict__ out)             // (B,N,C)
{
    const int pt = blockIdx.x;          // 0 .. BB*NN-1
    const int b  = pt / NN;
    const int n  = pt % NN;
    const int c  = threadIdx.x;         // 0..127  (thread == output channel)

    __shared__ float s_t[2][CC];        // double-buffered t vector per k
    __shared__ float s_res[CC];
    __shared__ float s_red0[2];
    __shared__ float s_red1[2];

    // ---- register-cache w_gcm column c : wcol[r] = w_gcm[r][c] ----
    // (coalesced across threads for each r; L1/L2-hit after the first blocks)
    float wcol[CC];
    #pragma unroll
    for (int r = 0; r < CC; ++r) wcol[r] = w_gcm[r * CC + c];

    // ---- w_pos column c and biases ----
    float wpos[GEO];
    #pragma unroll
    for (int g = 0; g < GEO; ++g) wpos[g] = w_pos[g * CC + c];
    const float bpos = b_pos[c];
    const float bgcm = b_gcm[c];

    // ---- center xyz (uniform across block -> scalar loads) ----
    const size_t prow = (size_t)(b * NN + n);
    const float cx = points[prow * 3 + 0];
    const float cy = points[prow * 3 + 1];
    const float cz = points[prow * 3 + 2];

    const int* idxp = gidx + prow * KK;
    const float feat_c = features[prow * CC + c];

    float pooled = 0.0f;   // h = relu(..) >= 0, so 0-init == exact max over h

    for (int k = 0; k < KK; ++k) {
        const int kn = idxp[k];
        const size_t nrow = (size_t)(b * NN + kn);
        const float gx = points[nrow * 3 + 0];
        const float gy = points[nrow * 3 + 1];
        const float gz = points[nrow * 3 + 2];
        const float dx = gx - cx, dy = gy - cy, dz = gz - cz;
        const float dist = sqrtf(dx * dx + dy * dy + dz * dz);

        // expanded_f[c] = geo . w_pos[:,c] + b_pos[c]
        // geo = [center(3), grouped_xyz(3), diff(3), dist(1)]
        float ef = bpos;
        ef += cx * wpos[0] + cy * wpos[1] + cz * wpos[2];
        ef += gx * wpos[3] + gy * wpos[4] + gz * wpos[5];
        ef += dx * wpos[6] + dy * wpos[7] + dz * wpos[8];
        ef += dist * wpos[9];

        const float gf = features[nrow * CC + c];

        const int buf = k & 1;
        s_t[buf][c] = gf + ef;
        __syncthreads();

        // h[c] = relu( t . w_gcm[:,c] + b_gcm[c] )
        float acc = bgcm;
        const float4* tp = (const float4*)s_t[buf];
        #pragma unroll
        for (int r4 = 0; r4 < CC / 4; ++r4) {
            const float4 t4 = tp[r4];
            acc += t4.x * wcol[4 * r4 + 0];
            acc += t4.y * wcol[4 * r4 + 1];
            acc += t4.z * wcol[4 * r4 + 2];
            acc += t4.w * wcol[4 * r4 + 3];
        }
        const float h = fmaxf(acc, 0.0f);
        pooled = fmaxf(pooled, h);
        // next iter writes the OTHER buffer; the sync above makes reuse of
        // this buffer (2 iters later) safe.
    }

    // ---- residual + out projection ----
    const float res = pooled + feat_c;
    s_res[c] = res;
    __syncthreads();

    float o = b_out[c];
    const float4* rp = (const float4*)s_res;
    #pragma unroll
    for (int r4 = 0; r4 < CC / 4; ++r4) {
        const float4 t4 = rp[r4];
        o += t4.x * w_out[(4 * r4 + 0) * CC + c];
        o += t4.y * w_out[(4 * r4 + 1) * CC + c];
        o += t4.z * w_out[(4 * r4 + 2) * CC + c];
        o += t4.w * w_out[(4 * r4 + 3) * CC + c];
    }

    // ---- LayerNorm over the 128 channels (2 waves) ----
    const int lane = threadIdx.x & 63;
    const int wid  = threadIdx.x >> 6;

    float v = o;
    #pragma unroll
    for (int off = 32; off > 0; off >>= 1) v += __shfl_down(v, off, 64);
    if (lane == 0) s_red0[wid] = v;
    __syncthreads();
    const float mu = (s_red0[0] + s_red0[1]) * (1.0f / CC);

    const float d = o - mu;
    float v2 = d * d;
    #pragma unroll
    for (int off = 32; off > 0; off >>= 1) v2 += __shfl_down(v2, off, 64);
    if (lane == 0) s_red1[wid] = v2;
    __syncthreads();
    const float var = (s_red1[0] + s_red1[1]) * (1.0f / CC);

    const float y = d * (1.0f / sqrtf(var + LN_EPS)) * ln_g[c] + ln_b[c];
    out[pt * (size_t)CC + c] = fmaxf(y, 0.0f);
}

extern "C" void kernel_launch(void* const* d_in, const int* in_sizes, int n_in,
                              void* d_out, int out_size, void* d_ws, size_t ws_size,
                              hipStream_t stream) {
    const float* points   = (const float*)d_in[0];
    const float* features = (const float*)d_in[1];
    const int*   gidx     = (const int*)  d_in[2];
    const float* w_pos    = (const float*)d_in[3];
    const float* b_pos    = (const float*)d_in[4];
    const float* w_gcm    = (const float*)d_in[5];
    const float* b_gcm    = (const float*)d_in[6];
    const float* w_out    = (const float*)d_in[7];
    const float* b_out    = (const float*)d_in[8];
    const float* ln_g     = (const float*)d_in[9];
    const float* ln_b     = (const float*)d_in[10];
    float* out = (float*)d_out;

    dim3 grid(BB * NN);
    dim3 block(CC);
    hipLaunchKernelGGL(bridge_kernel, grid, block, 0, stream,
                       points, features, gidx, w_pos, b_pos, w_gcm, b_gcm,
                       w_out, b_out, ln_g, ln_b, out);
}

// Round 4
// 277.785 us; speedup vs baseline: 4.1070x; 4.1070x over previous
//
#include <hip/hip_runtime.h>
#include <hip/hip_bf16.h>
#include <math.h>

typedef __attribute__((ext_vector_type(8))) short short8;
typedef __attribute__((ext_vector_type(4))) float float4v;

constexpr int NPTS = 32768;  // B*N
constexpr int NN   = 16384;  // points per batch
constexpr int KK   = 32;     // neighbors
constexpr int CC   = 128;    // channels
constexpr int KW   = 160;    // folded K: 128 features + 10 geo + 22 zero-pad
constexpr int SA   = 168;    // LDS A row stride (bf16 elems): 336B -> 2-way banks (free)
constexpr int SR   = 136;    // LDS res row stride: 272B -> 2-way banks (free)
constexpr int GRP  = 32;     // points per block (divides NN -> block never straddles batches)
#define LN_EPS 1e-5f

__device__ __forceinline__ short f2bs(float x) {
    return (short)__builtin_bit_cast(unsigned short, __float2bfloat16(x));
}

// ---------------- prep: fold weights, swizzle to [k/8][n][k%8] bf16 ----------------
__global__ __launch_bounds__(256) void prep_kernel(
    const float* __restrict__ w_pos, const float* __restrict__ b_pos,
    const float* __restrict__ w_gcm, const float* __restrict__ b_gcm,
    const float* __restrict__ w_out,
    short* __restrict__ wsWp, short* __restrict__ wsWo, float* __restrict__ wsBeff)
{
    __shared__ float swpg[10][128];
    const int t = threadIdx.x;
    if (t < 128) {
        float wb = b_gcm[t];
        for (int r = 0; r < 128; ++r) wb += b_pos[r] * w_gcm[r * 128 + t];
        wsBeff[t] = wb;
        for (int g = 0; g < 10; ++g) {
            float s = 0.f;
            for (int r = 0; r < 128; ++r) s += w_pos[g * 128 + r] * w_gcm[r * 128 + t];
            swpg[g][t] = s;
        }
    }
    __syncthreads();
    // W' = [w_gcm (128) ; w_pos@w_gcm (10) ; 0 (22)]  packed (g,n,j), k=8g+j
    for (int e = t; e < (KW / 8) * 128 * 8; e += 256) {
        int j = e & 7, n = (e >> 3) & 127, g = e >> 10;
        int k = g * 8 + j;
        float v = (k < 128) ? w_gcm[k * 128 + n] : (k < 138 ? swpg[k - 128][n] : 0.f);
        wsWp[e] = f2bs(v);
    }
    for (int e = t; e < 128 * 128; e += 256) {
        int j = e & 7, n = (e >> 3) & 127, g = e >> 10;
        wsWo[e] = f2bs(w_out[(g * 8 + j) * 128 + n]);
    }
}

// ---------------- main: gather -> MFMA GEMM -> pool -> res -> MFMA out-proj -> LN ----------------
__global__ __launch_bounds__(256) void bridge_mfma_kernel(
    const float* __restrict__ points, const float* __restrict__ features,
    const int*   __restrict__ gidx,
    const short* __restrict__ wsWp, const short* __restrict__ wsWo,
    const float* __restrict__ wsBeff,
    const float* __restrict__ b_out, const float* __restrict__ ln_g,
    const float* __restrict__ ln_b,
    float* __restrict__ out)
{
    __shared__ short sA[2][KK * SA];      // double-buffered A tile (bf16)
    __shared__ short sRes[GRP * SR];      // res rows (bf16)
    __shared__ float sPS[4][GRP], sPQ[4][GRP];

    const int t    = threadIdx.x;
    const int wv   = t >> 6;
    const int quad = (t >> 4) & 3;
    const int m    = t & 15;
    const int row  = t >> 3;              // gather row 0..31
    const int t7   = t & 7;
    const int g0   = blockIdx.x * GRP;
    const int nbase = (g0 / NN) * NN;     // batch base for per-batch gather indices

    // ---- B fragments (register-resident): lane holds B[k=quad*8+j][n] ----
    const int col0 = wv * 32 + m;         // ntl=0 column; ntl=1 is col0+16
    short8 bWp[5][2];
    #pragma unroll
    for (int ks = 0; ks < 5; ++ks)
        #pragma unroll
        for (int ntl = 0; ntl < 2; ++ntl)
            bWp[ks][ntl] = *((const short8*)wsWp + ((ks * 4 + quad) * 128 + col0 + ntl * 16));

    float beffv[2], boutv[2], lngv[2], lnbv[2];
    #pragma unroll
    for (int ntl = 0; ntl < 2; ++ntl) {
        int c = col0 + ntl * 16;
        beffv[ntl] = wsBeff[c]; boutv[ntl] = b_out[c];
        lngv[ntl] = ln_g[c];    lnbv[ntl] = ln_b[c];
    }

    // ---- build pipeline: load(p) -> regs; store(p) -> LDS ----
    int   kn;
    float4 fa0, fb0, fa1, fb1;
    float cx, cy, cz, gx, gy, gz;

    auto load_pt = [&](int p) {
        const int pt = g0 + p;
        kn = nbase + gidx[pt * KK + row];          // per-batch index -> global row
        const float4* fp = (const float4*)(features + (size_t)kn * CC);
        fa0 = fp[2 * t7 + 0];  fb0 = fp[2 * t7 + 1];
        fa1 = fp[2 * (t7 + 8) + 0];  fb1 = fp[2 * (t7 + 8) + 1];
        if (t7 == 7) {
            cx = points[pt * 3 + 0]; cy = points[pt * 3 + 1]; cz = points[pt * 3 + 2];
            gx = points[kn * 3 + 0]; gy = points[kn * 3 + 1]; gz = points[kn * 3 + 2];
        }
    };
    auto store_pt = [&](int buf) {
        short* arow = &sA[buf][row * SA];
        short8 v;
        v[0]=f2bs(fa0.x); v[1]=f2bs(fa0.y); v[2]=f2bs(fa0.z); v[3]=f2bs(fa0.w);
        v[4]=f2bs(fb0.x); v[5]=f2bs(fb0.y); v[6]=f2bs(fb0.z); v[7]=f2bs(fb0.w);
        *(short8*)(arow + t7 * 8) = v;
        v[0]=f2bs(fa1.x); v[1]=f2bs(fa1.y); v[2]=f2bs(fa1.z); v[3]=f2bs(fa1.w);
        v[4]=f2bs(fb1.x); v[5]=f2bs(fb1.y); v[6]=f2bs(fb1.z); v[7]=f2bs(fb1.w);
        *(short8*)(arow + (t7 + 8) * 8) = v;
        if (t7 == 7) {
            const float dx = gx - cx, dy = gy - cy, dz = gz - cz;
            const float dist = sqrtf(dx * dx + dy * dy + dz * dz);
            short8 v0, v1;
            v0[0]=f2bs(cx); v0[1]=f2bs(cy); v0[2]=f2bs(cz);
            v0[3]=f2bs(gx); v0[4]=f2bs(gy); v0[5]=f2bs(gz);
            v0[6]=f2bs(dx); v0[7]=f2bs(dy);
            v1 = (short8)0; v1[0]=f2bs(dz); v1[1]=f2bs(dist);
            *(short8*)(arow + 128) = v0;
            *(short8*)(arow + 136) = v1;
            *(short8*)(arow + 144) = (short8)0;
            *(short8*)(arow + 152) = (short8)0;
        }
    };

    load_pt(0);
    store_pt(0);
    __syncthreads();

    for (int p = 0; p < GRP; ++p) {
        if (p < GRP - 1) load_pt(p + 1);          // global loads in flight over MFMA

        const short* ab  = sA[p & 1];
        const short* am0 = ab + m * SA;
        const short* am1 = ab + (16 + m) * SA;
        float4v acc[2][2] = {};
        #pragma unroll
        for (int ks = 0; ks < 5; ++ks) {
            short8 a0 = *(const short8*)(am0 + ks * 32 + quad * 8);
            short8 a1 = *(const short8*)(am1 + ks * 32 + quad * 8);
            #pragma unroll
            for (int ntl = 0; ntl < 2; ++ntl) {
                acc[0][ntl] = __builtin_amdgcn_mfma_f32_16x16x32_bf16(a0, bWp[ks][ntl], acc[0][ntl], 0, 0, 0);
                acc[1][ntl] = __builtin_amdgcn_mfma_f32_16x16x32_bf16(a1, bWp[ks][ntl], acc[1][ntl], 0, 0, 0);
            }
        }

        if (p < GRP - 1) store_pt((p + 1) & 1);   // cvt + ds_write after MFMA issued

        // ---- relu+max-pool over 32 rows, residual, stash res ----
        const int pt = g0 + p;
        #pragma unroll
        for (int ntl = 0; ntl < 2; ++ntl) {
            float v = acc[0][ntl][0];
            #pragma unroll
            for (int r = 1; r < 4; ++r) v = fmaxf(v, acc[0][ntl][r]);
            #pragma unroll
            for (int r = 0; r < 4; ++r) v = fmaxf(v, acc[1][ntl][r]);
            v = fmaxf(v, __shfl_xor(v, 16));
            v = fmaxf(v, __shfl_xor(v, 32));
            v = fmaxf(v + beffv[ntl], 0.f);                      // relu(max + bias)
            float res = v + features[(size_t)pt * CC + col0 + ntl * 16];
            if (quad == 0) sRes[p * SR + col0 + ntl * 16] = f2bs(res);
        }
        __syncthreads();
    }

    // ---- out projection: res(32x128) @ w_out(128x128) ----
    short8 bWo[4][2];
    #pragma unroll
    for (int ks = 0; ks < 4; ++ks)
        #pragma unroll
        for (int ntl = 0; ntl < 2; ++ntl)
            bWo[ks][ntl] = *((const short8*)wsWo + ((ks * 4 + quad) * 128 + col0 + ntl * 16));

    const short* rm0 = sRes + m * SR;
    const short* rm1 = sRes + (16 + m) * SR;
    float4v acc2[2][2] = {};
    #pragma unroll
    for (int ks = 0; ks < 4; ++ks) {
        short8 a0 = *(const short8*)(rm0 + ks * 32 + quad * 8);
        short8 a1 = *(const short8*)(rm1 + ks * 32 + quad * 8);
        #pragma unroll
        for (int ntl = 0; ntl < 2; ++ntl) {
            acc2[0][ntl] = __builtin_amdgcn_mfma_f32_16x16x32_bf16(a0, bWo[ks][ntl], acc2[0][ntl], 0, 0, 0);
            acc2[1][ntl] = __builtin_amdgcn_mfma_f32_16x16x32_bf16(a1, bWo[ks][ntl], acc2[1][ntl], 0, 0, 0);
        }
    }

    // ---- LayerNorm partials: rows R = mt*16 + quad*4 + r ----
    #pragma unroll
    for (int mt = 0; mt < 2; ++mt)
        #pragma unroll
        for (int r = 0; r < 4; ++r) {
            float o0 = acc2[mt][0][r] + boutv[0];
            float o1 = acc2[mt][1][r] + boutv[1];
            float ss = o0 + o1, qq = o0 * o0 + o1 * o1;
            #pragma unroll
            for (int d = 1; d < 16; d <<= 1) {
                ss += __shfl_xor(ss, d);
                qq += __shfl_xor(qq, d);
            }
            if (m == 0) {
                sPS[wv][mt * 16 + quad * 4 + r] = ss;
                sPQ[wv][mt * 16 + quad * 4 + r] = qq;
            }
        }
    __syncthreads();

    #pragma unroll
    for (int mt = 0; mt < 2; ++mt)
        #pragma unroll
        for (int r = 0; r < 4; ++r) {
            const int R = mt * 16 + quad * 4 + r;
            const float S  = sPS[0][R] + sPS[1][R] + sPS[2][R] + sPS[3][R];
            const float Q  = sPQ[0][R] + sPQ[1][R] + sPQ[2][R] + sPQ[3][R];
            const float mu = S * (1.f / 128.f);
            const float var = fmaxf(Q * (1.f / 128.f) - mu * mu, 0.f);
            const float rstd = rsqrtf(var + LN_EPS);
            const float o0 = acc2[mt][0][r] + boutv[0];
            const float o1 = acc2[mt][1][r] + boutv[1];
            const size_t base = (size_t)(g0 + R) * CC;
            out[base + col0]      = fmaxf((o0 - mu) * rstd * lngv[0] + lnbv[0], 0.f);
            out[base + col0 + 16] = fmaxf((o1 - mu) * rstd * lngv[1] + lnbv[1], 0.f);
        }
}

extern "C" void kernel_launch(void* const* d_in, const int* in_sizes, int n_in,
                              void* d_out, int out_size, void* d_ws, size_t ws_size,
                              hipStream_t stream) {
    const float* points   = (const float*)d_in[0];
    const float* features = (const float*)d_in[1];
    const int*   gidx     = (const int*)  d_in[2];
    const float* w_pos    = (const float*)d_in[3];
    const float* b_pos    = (const float*)d_in[4];
    const float* w_gcm    = (const float*)d_in[5];
    const float* b_gcm    = (const float*)d_in[6];
    const float* w_out    = (const float*)d_in[7];
    const float* b_out    = (const float*)d_in[8];
    const float* ln_g     = (const float*)d_in[9];
    const float* ln_b     = (const float*)d_in[10];
    float* out = (float*)d_out;

    char* ws = (char*)d_ws;
    short* wsWp   = (short*)ws;                    // 160*128 bf16 = 40960 B
    short* wsWo   = (short*)(ws + 40960);          // 128*128 bf16 = 32768 B
    float* wsBeff = (float*)(ws + 40960 + 32768);  // 128 f32

    hipLaunchKernelGGL(prep_kernel, dim3(1), dim3(256), 0, stream,
                       w_pos, b_pos, w_gcm, b_gcm, w_out, wsWp, wsWo, wsBeff);
    hipLaunchKernelGGL(bridge_mfma_kernel, dim3(NPTS / GRP), dim3(256), 0, stream,
                       points, features, gidx, wsWp, wsWo, wsBeff,
                       b_out, ln_g, ln_b, out);
}

// Round 5
// 174.930 us; speedup vs baseline: 6.5218x; 1.5880x over previous
//
#include <hip/hip_runtime.h>
#include <hip/hip_bf16.h>
#include <math.h>

typedef __attribute__((ext_vector_type(8))) short short8;
typedef __attribute__((ext_vector_type(4))) float float4v;
typedef unsigned short ushort_t;

constexpr int NPTS = 32768;  // B*N
constexpr int NN   = 16384;  // points per batch
constexpr int KK   = 32;     // neighbors
constexpr int CC   = 128;    // channels
constexpr int GRP  = 16;     // points per block -> grid 2048
constexpr int SG   = 40;     // geo LDS row stride (shorts): 80 B -> 2-way banks (free)
constexpr int SR   = 136;    // res LDS row stride (shorts): 272 B -> 2-way banks (free)
#define LN_EPS 1e-5f

// d_ws layout (bytes)
constexpr size_t WS_WP   = 0;        // W' swizzled: 20*128*8 bf16 = 40960 B
constexpr size_t WS_WO   = 40960;    // w_out swizzled: 128*128 bf16 = 32768 B
constexpr size_t WS_BE   = 73728;    // beff: 128 f32 = 512 B
constexpr size_t WS_FB   = 74240;    // features bf16: 32768*128*2 = 8388608 B
constexpr size_t WS_NEED = WS_FB + (size_t)NPTS * CC * 2;

__device__ __forceinline__ short f2bs(float x) {
    return (short)__builtin_bit_cast(unsigned short, __float2bfloat16(x));
}
__device__ __forceinline__ float bs2f(ushort_t u) {
    return __uint_as_float(((unsigned)u) << 16);
}

// ---------------- prep: fold weights + swizzle + (optional) bf16 feature convert ----------------
__global__ __launch_bounds__(256) void prep_kernel(
    const float* __restrict__ features,
    const float* __restrict__ w_pos, const float* __restrict__ b_pos,
    const float* __restrict__ w_gcm, const float* __restrict__ b_gcm,
    const float* __restrict__ w_out,
    short* __restrict__ wsWp, short* __restrict__ wsWo, float* __restrict__ wsBeff,
    ushort_t* __restrict__ featbf)
{
    const int t = threadIdx.x;
    const int blk = blockIdx.x;

    if (blk >= 2) {            // ---- feature f32 -> bf16, 2048 elems/block ----
        const size_t base = (size_t)(blk - 2) * 2048 + (size_t)t * 8;
        const float4* fp = (const float4*)(features + base);
        const float4 a = fp[0], b = fp[1];
        short8 v;
        v[0]=f2bs(a.x); v[1]=f2bs(a.y); v[2]=f2bs(a.z); v[3]=f2bs(a.w);
        v[4]=f2bs(b.x); v[5]=f2bs(b.y); v[6]=f2bs(b.z); v[7]=f2bs(b.w);
        *(short8*)(featbf + base) = v;
        return;
    }
    if (blk == 1) {            // ---- w_out -> swizzled bf16 [(k/8)(n)(k%8)] ----
        for (int e = t; e < 128 * 128; e += 256) {
            int j = e & 7, n = (e >> 3) & 127, g = e >> 10;
            wsWo[e] = f2bs(w_out[(g * 8 + j) * 128 + n]);
        }
        return;
    }
    // ---- block 0: stage w_gcm in LDS, fold w_pos/b_pos, emit W' + beff ----
    __shared__ float sW[128 * 128];
    __shared__ float sPG[10 * 128];
    for (int e = t; e < 4096; e += 256) ((float4*)sW)[e] = ((const float4*)w_gcm)[e];
    __syncthreads();
    {
        const int c  = t & 127;
        const int gb = t >> 7;
        for (int gi = 0; gi < 5; ++gi) {
            const int g = gi * 2 + gb;
            float s = 0.f;
            for (int r = 0; r < 128; ++r) s += w_pos[g * 128 + r] * sW[r * 128 + c];
            sPG[g * 128 + c] = s;
        }
        if (t < 128) {
            float wb = b_gcm[t];
            for (int r = 0; r < 128; ++r) wb += b_pos[r] * sW[r * 128 + t];
            wsBeff[t] = wb;
        }
    }
    __syncthreads();
    for (int e = t; e < 20 * 128 * 8; e += 256) {
        const int j = e & 7, n = (e >> 3) & 127, g = e >> 10;
        const int k = g * 8 + j;
        const float v = (k < 128) ? sW[k * 128 + n] : (k < 138 ? sPG[(k - 128) * 128 + n] : 0.f);
        wsWp[e] = f2bs(v);
    }
}

// ---------------- main kernel (DMA=1: async bf16 gather; DMA=0: f32 VALU gather fallback) ----------------
template<int DMA>
__global__ __launch_bounds__(256) void bridge_main(
    const float* __restrict__ points, const float* __restrict__ features,
    const int*   __restrict__ gidx,
    const short* __restrict__ wsWp, const short* __restrict__ wsWo,
    const float* __restrict__ wsBeff, const ushort_t* __restrict__ featbf,
    const float* __restrict__ b_out, const float* __restrict__ ln_g,
    const float* __restrict__ ln_b,
    float* __restrict__ out)
{
    __shared__ short sA[2][KK * CC];    // gathered features, 256B rows, XOR-chunk-swizzled
    __shared__ short sG[2][KK * SG];    // geo cols 128..159 (10 real + zeros), padded stride
    __shared__ short sRes[GRP * SR];
    __shared__ int   sIdx[GRP * KK];    // 512 neighbor indices
    __shared__ float sPS[4][GRP], sPQ[4][GRP];

    const int t = threadIdx.x, wv = t >> 6, lane = t & 63;
    const int quad = (t >> 4) & 3, m = t & 15;
    const int g0 = blockIdx.x * GRP;
    const int nbase = (g0 >= NN) ? NN : 0;    // batch base (GRP divides NN)
    const int col0 = wv * 32 + m;

    // ---- stage idx, zero geo pad columns (cols 144..159 of each row, both bufs) ----
    sIdx[t]       = gidx[(size_t)g0 * KK + t];
    sIdx[t + 256] = gidx[(size_t)g0 * KK + t + 256];
    if (t < 128) {
        const int b = t >> 6, r = (t >> 1) & 31, h = t & 1;
        *(short8*)&sG[b][r * SG + 16 + h * 8] = (short8)0;
    }

    // ---- B fragments + per-column constants ----
    short8 bWp[5][2];
    #pragma unroll
    for (int ks = 0; ks < 5; ++ks)
        #pragma unroll
        for (int ntl = 0; ntl < 2; ++ntl)
            bWp[ks][ntl] = *((const short8*)wsWp + ((ks * 4 + quad) * 128 + col0 + ntl * 16));
    float beffv[2] = { wsBeff[col0], wsBeff[col0 + 16] };

    __syncthreads();

    // ---- gather lane mapping: 16 lanes per row, XOR chunk swizzle ----
    const int r0 = wv * 4 + (lane >> 4);  // 0..15 (row r0 and r0+16)
    const int pc = lane & 15;             // physical 16B chunk
    const int gc = pc ^ r0;               // global (logical) chunk; (r0+16)&15 == r0

    float4 ff0a, ff0b, ff1a, ff1b;                    // fallback regs
    float gcx, gcy, gcz, ggx, ggy, ggz;               // geo regs (lane<8)

    auto issue_dma = [&](int p, int buf) {
        const int kn0 = nbase + sIdx[p * KK + r0];
        const int kn1 = nbase + sIdx[p * KK + r0 + 16];
        const ushort_t* gp0 = featbf + (size_t)kn0 * CC + gc * 8;
        const ushort_t* gp1 = featbf + (size_t)kn1 * CC + gc * 8;
        short* l0 = &sA[buf][(wv * 4) * CC];          // wave-uniform; lane i -> +i*16B
        short* l1 = &sA[buf][(wv * 4 + 16) * CC];
        __builtin_amdgcn_global_load_lds((const __attribute__((address_space(1))) void*)gp0,
                                         (__attribute__((address_space(3))) void*)l0, 16, 0, 0);
        __builtin_amdgcn_global_load_lds((const __attribute__((address_space(1))) void*)gp1,
                                         (__attribute__((address_space(3))) void*)l1, 16, 0, 0);
    };
    auto fb_load = [&](int p) {
        const int kn0 = nbase + sIdx[p * KK + r0];
        const int kn1 = nbase + sIdx[p * KK + r0 + 16];
        const float4* f0 = (const float4*)(features + (size_t)kn0 * CC + gc * 8);
        const float4* f1 = (const float4*)(features + (size_t)kn1 * CC + gc * 8);
        ff0a = f0[0]; ff0b = f0[1]; ff1a = f1[0]; ff1b = f1[1];
    };
    auto fb_store = [&](int buf) {
        short8 v;
        v[0]=f2bs(ff0a.x); v[1]=f2bs(ff0a.y); v[2]=f2bs(ff0a.z); v[3]=f2bs(ff0a.w);
        v[4]=f2bs(ff0b.x); v[5]=f2bs(ff0b.y); v[6]=f2bs(ff0b.z); v[7]=f2bs(ff0b.w);
        *(short8*)&sA[buf][r0 * CC + pc * 8] = v;
        v[0]=f2bs(ff1a.x); v[1]=f2bs(ff1a.y); v[2]=f2bs(ff1a.z); v[3]=f2bs(ff1a.w);
        v[4]=f2bs(ff1b.x); v[5]=f2bs(ff1b.y); v[6]=f2bs(ff1b.z); v[7]=f2bs(ff1b.w);
        *(short8*)&sA[buf][(r0 + 16) * CC + pc * 8] = v;
    };
    auto geo_load = [&](int p) {
        if (lane < 8) {
            const int j  = wv * 8 + lane;
            const int pt = g0 + p;
            const int kn = nbase + sIdx[p * KK + j];
            gcx = points[(size_t)pt * 3 + 0]; gcy = points[(size_t)pt * 3 + 1]; gcz = points[(size_t)pt * 3 + 2];
            ggx = points[(size_t)kn * 3 + 0]; ggy = points[(size_t)kn * 3 + 1]; ggz = points[(size_t)kn * 3 + 2];
        }
    };
    auto geo_store = [&](int buf) {
        if (lane < 8) {
            const int j = wv * 8 + lane;
            const float dx = ggx - gcx, dy = ggy - gcy, dz = ggz - gcz;
            const float dist = sqrtf(dx * dx + dy * dy + dz * dz);
            short8 v0, v1 = (short8)0;
            v0[0]=f2bs(gcx); v0[1]=f2bs(gcy); v0[2]=f2bs(gcz);
            v0[3]=f2bs(ggx); v0[4]=f2bs(ggy); v0[5]=f2bs(ggz);
            v0[6]=f2bs(dx);  v0[7]=f2bs(dy);
            v1[0]=f2bs(dz);  v1[1]=f2bs(dist);
            *(short8*)&sG[buf][j * SG + 0] = v0;
            *(short8*)&sG[buf][j * SG + 8] = v1;
        }
    };

    // ---- preload point 0 ----
    if constexpr (DMA) issue_dma(0, 0); else fb_load(0);
    geo_load(0);
    if constexpr (!DMA) fb_store(0);
    geo_store(0);
    __syncthreads();

    // loop-invariant A-fragment offsets (shorts)
    int offA[4];
    #pragma unroll
    for (int ks = 0; ks < 4; ++ks) offA[ks] = m * CC + (((ks * 4 + quad) ^ m) * 8);
    const int offG = m * SG + quad * 8;

    for (int p = 0; p < GRP; ++p) {
        const int buf = p & 1, nbuf = buf ^ 1;
        if (p + 1 < GRP) {
            if constexpr (DMA) issue_dma(p + 1, nbuf); else fb_load(p + 1);
            geo_load(p + 1);
        }

        const short* ab = sA[buf];
        const short* ag = sG[buf];
        float4v acc[2][2] = {};
        #pragma unroll
        for (int ks = 0; ks < 4; ++ks) {
            const short8 a0 = *(const short8*)(ab + offA[ks]);
            const short8 a1 = *(const short8*)(ab + offA[ks] + 16 * CC);
            acc[0][0] = __builtin_amdgcn_mfma_f32_16x16x32_bf16(a0, bWp[ks][0], acc[0][0], 0, 0, 0);
            acc[0][1] = __builtin_amdgcn_mfma_f32_16x16x32_bf16(a0, bWp[ks][1], acc[0][1], 0, 0, 0);
            acc[1][0] = __builtin_amdgcn_mfma_f32_16x16x32_bf16(a1, bWp[ks][0], acc[1][0], 0, 0, 0);
            acc[1][1] = __builtin_amdgcn_mfma_f32_16x16x32_bf16(a1, bWp[ks][1], acc[1][1], 0, 0, 0);
        }
        {
            const short8 a0 = *(const short8*)(ag + offG);
            const short8 a1 = *(const short8*)(ag + offG + 16 * SG);
            acc[0][0] = __builtin_amdgcn_mfma_f32_16x16x32_bf16(a0, bWp[4][0], acc[0][0], 0, 0, 0);
            acc[0][1] = __builtin_amdgcn_mfma_f32_16x16x32_bf16(a0, bWp[4][1], acc[0][1], 0, 0, 0);
            acc[1][0] = __builtin_amdgcn_mfma_f32_16x16x32_bf16(a1, bWp[4][0], acc[1][0], 0, 0, 0);
            acc[1][1] = __builtin_amdgcn_mfma_f32_16x16x32_bf16(a1, bWp[4][1], acc[1][1], 0, 0, 0);
        }

        if (p + 1 < GRP) {
            if constexpr (!DMA) fb_store(nbuf);
            geo_store(nbuf);
        }

        // ---- relu+max-pool over 32 neighbors, residual, stash res ----
        const int pt = g0 + p;
        #pragma unroll
        for (int ntl = 0; ntl < 2; ++ntl) {
            float v = acc[0][ntl][0];
            #pragma unroll
            for (int r = 1; r < 4; ++r) v = fmaxf(v, acc[0][ntl][r]);
            #pragma unroll
            for (int r = 0; r < 4; ++r) v = fmaxf(v, acc[1][ntl][r]);
            v = fmaxf(v, __shfl_xor(v, 16));
            v = fmaxf(v, __shfl_xor(v, 32));
            v = fmaxf(v + beffv[ntl], 0.f);
            float fc;
            if constexpr (DMA) fc = bs2f(featbf[(size_t)pt * CC + col0 + ntl * 16]);
            else               fc = features[(size_t)pt * CC + col0 + ntl * 16];
            const float res = v + fc;
            if (quad == 0) sRes[p * SR + col0 + ntl * 16] = f2bs(res);
        }
        __syncthreads();
    }

    // ---- out projection: res(16x128) @ w_out(128x128) ----
    short8 bWo[4][2];
    #pragma unroll
    for (int ks = 0; ks < 4; ++ks)
        #pragma unroll
        for (int ntl = 0; ntl < 2; ++ntl)
            bWo[ks][ntl] = *((const short8*)wsWo + ((ks * 4 + quad) * 128 + col0 + ntl * 16));

    const short* rm = sRes + m * SR;
    float4v acc2[2] = {};
    #pragma unroll
    for (int ks = 0; ks < 4; ++ks) {
        const short8 a = *(const short8*)(rm + ks * 32 + quad * 8);
        acc2[0] = __builtin_amdgcn_mfma_f32_16x16x32_bf16(a, bWo[ks][0], acc2[0], 0, 0, 0);
        acc2[1] = __builtin_amdgcn_mfma_f32_16x16x32_bf16(a, bWo[ks][1], acc2[1], 0, 0, 0);
    }

    const float boutv[2] = { b_out[col0], b_out[col0 + 16] };
    const float lngv[2]  = { ln_g[col0], ln_g[col0 + 16] };
    const float lnbv[2]  = { ln_b[col0], ln_b[col0 + 16] };

    #pragma unroll
    for (int r = 0; r < 4; ++r) {
        const float o0 = acc2[0][r] + boutv[0];
        const float o1 = acc2[1][r] + boutv[1];
        float ss = o0 + o1, qq = o0 * o0 + o1 * o1;
        #pragma unroll
        for (int d = 1; d < 16; d <<= 1) { ss += __shfl_xor(ss, d); qq += __shfl_xor(qq, d); }
        if (m == 0) { sPS[wv][quad * 4 + r] = ss; sPQ[wv][quad * 4 + r] = qq; }
    }
    __syncthreads();

    #pragma unroll
    for (int r = 0; r < 4; ++r) {
        const int R = quad * 4 + r;
        const float S = sPS[0][R] + sPS[1][R] + sPS[2][R] + sPS[3][R];
        const float Q = sPQ[0][R] + sPQ[1][R] + sPQ[2][R] + sPQ[3][R];
        const float mu  = S * (1.f / 128.f);
        const float var = fmaxf(Q * (1.f / 128.f) - mu * mu, 0.f);
        const float rstd = rsqrtf(var + LN_EPS);
        const float o0 = acc2[0][r] + boutv[0];
        const float o1 = acc2[1][r] + boutv[1];
        const size_t base = (size_t)(g0 + R) * CC;
        out[base + col0]      = fmaxf((o0 - mu) * rstd * lngv[0] + lnbv[0], 0.f);
        out[base + col0 + 16] = fmaxf((o1 - mu) * rstd * lngv[1] + lnbv[1], 0.f);
    }
}

extern "C" void kernel_launch(void* const* d_in, const int* in_sizes, int n_in,
                              void* d_out, int out_size, void* d_ws, size_t ws_size,
                              hipStream_t stream) {
    const float* points   = (const float*)d_in[0];
    const float* features = (const float*)d_in[1];
    const int*   gidx     = (const int*)  d_in[2];
    const float* w_pos    = (const float*)d_in[3];
    const float* b_pos    = (const float*)d_in[4];
    const float* w_gcm    = (const float*)d_in[5];
    const float* b_gcm    = (const float*)d_in[6];
    const float* w_out    = (const float*)d_in[7];
    const float* b_out    = (const float*)d_in[8];
    const float* ln_g     = (const float*)d_in[9];
    const float* ln_b     = (const float*)d_in[10];
    float* out = (float*)d_out;

    char* ws = (char*)d_ws;
    short*    wsWp   = (short*)(ws + WS_WP);
    short*    wsWo   = (short*)(ws + WS_WO);
    float*    wsBeff = (float*)(ws + WS_BE);
    ushort_t* featbf = (ushort_t*)(ws + WS_FB);

    const bool use_dma = (ws_size >= WS_NEED);
    const int prep_blocks = use_dma ? (2 + NPTS * CC / 2048) : 2;   // 2 + 2048

    hipLaunchKernelGGL(prep_kernel, dim3(prep_blocks), dim3(256), 0, stream,
                       features, w_pos, b_pos, w_gcm, b_gcm, w_out,
                       wsWp, wsWo, wsBeff, featbf);
    if (use_dma) {
        hipLaunchKernelGGL((bridge_main<1>), dim3(NPTS / GRP), dim3(256), 0, stream,
                           points, features, gidx, wsWp, wsWo, wsBeff, featbf,
                           b_out, ln_g, ln_b, out);
    } else {
        hipLaunchKernelGGL((bridge_main<0>), dim3(NPTS / GRP), dim3(256), 0, stream,
                           points, features, gidx, wsWp, wsWo, wsBeff, featbf,
                           b_out, ln_g, ln_b, out);
    }
}